// Round 7
// baseline (105.622 us; speedup 1.0000x reference)
//
#include <hip/hip_runtime.h>
#include <hip/hip_bf16.h>

#define NB 16
#define NC 256
#define NH 64
#define NW 64

typedef __attribute__((ext_vector_type(8))) short bf16x8;
typedef __attribute__((ext_vector_type(4))) float f32x4;

__device__ __forceinline__ unsigned short f2bf(float f) {
    union { float f; unsigned int u; } v; v.f = f;
    unsigned int u = v.u;
    u += 0x7fffu + ((u >> 16) & 1u);   // round-to-nearest-even
    return (unsigned short)(u >> 16);
}

// 16B-slot XOR swizzle; conflict-free for our write patterns, <=2-way reads
__device__ __forceinline__ int swzT(int row, int col) {   // [rows][256] tile
    return row * 256 + ((((col >> 3) ^ (row & 7) ^ ((row >> 3) & 7)) << 3) | (col & 7));
}
__device__ __forceinline__ int swzS(int row, int col) {   // [rows][64] tile
    return row * 64 + ((((col >> 3) ^ (row & 7) ^ ((row >> 3) & 7)) << 3) | (col & 7));
}

// ---- prep: G = Wq^T Wk (bf16), u = Wk^T bq, v = Wq^T bk (bf16), s = bq.bk ----
__global__ void prep_g(const float* __restrict__ wq, const float* __restrict__ wk,
                       const float* __restrict__ bq, const float* __restrict__ bk,
                       unsigned short* __restrict__ wsb) {
    int c2 = threadIdx.x;
    if (blockIdx.x < 32) {
        int c1_0 = blockIdx.x * 8;
        float acc[8] = {0.f, 0.f, 0.f, 0.f, 0.f, 0.f, 0.f, 0.f};
        for (int o = 0; o < 256; ++o) {
            float wkv = wk[o * 256 + c2];
            #pragma unroll
            for (int i = 0; i < 8; ++i)
                acc[i] += wq[o * 256 + c1_0 + i] * wkv;
        }
        #pragma unroll
        for (int i = 0; i < 8; ++i)
            wsb[(c1_0 + i) * 256 + c2] = f2bf(acc[i]);
    } else {
        float u = 0.f, v = 0.f;
        #pragma unroll 4
        for (int o = 0; o < 256; ++o) {
            u += bq[o] * wk[o * 256 + c2];
            v += bk[o] * wq[o * 256 + c2];
        }
        wsb[131072 + c2] = f2bf(u);
        wsb[131328 + c2] = f2bf(v);
        if (c2 == 0) {
            float s = 0.f;
            for (int o = 0; o < 256; ++o) s += bq[o] * bk[o];
            *(float*)(wsb + 131584) = s;
        }
    }
}

__global__ void prep_wv(const float* __restrict__ wv, unsigned short* __restrict__ wsb) {
    int i = blockIdx.x * 256 + threadIdx.x;   // 16384 float4s total
    float4 t = ((const float4*)wv)[i];
    ushort4 u = { f2bf(t.x), f2bf(t.y), f2bf(t.z), f2bf(t.w) };
    ((ushort4*)(wsb + 65536))[i] = u;
}

// LDS: AT [64 w][256 c] @0 | TT [64 x][256 c1] -> later Vs [256 c][64 x] @16384 |
//      ATT [64 w][64 x] @32768 | uAvA[128] f32.  Total 74,240 B -> 2 blocks/CU.
// V result lives in registers from P4-compute until TT is dead (post-P3).
__launch_bounds__(512, 4)
__global__ void mha_fused(const float* __restrict__ a,
                          const unsigned short* __restrict__ wsb,
                          const float* __restrict__ bv,
                          float* __restrict__ out) {
    __shared__ __align__(16) unsigned short smem[36864];
    __shared__ __align__(16) float uAvA[128];
    unsigned short* AT  = smem;
    unsigned short* TT  = smem + 16384;
    unsigned short* Vs  = smem + 16384;   // aliases TT; written only after P3
    unsigned short* ATT = smem + 32768;

    const unsigned short* Gb  = wsb;
    const unsigned short* Wvb = wsb + 65536;
    const unsigned short* ub  = wsb + 131072;
    const unsigned short* vbv = wsb + 131328;

    const int tid = threadIdx.x;
    const int b = blockIdx.x >> 6;
    const int h = blockIdx.x & 63;
    const float* aB = a + (size_t)b * (NC * NH * NW) + h * NW;

    // ---- P1: global [c][w] fp32 -> reg 4x4 transpose -> AT[w][c] bf16 ----
    #pragma unroll
    for (int half = 0; half < 2; ++half) {
        int mt = tid + half * 512;
        int c0 = (mt >> 4) << 2;
        int w0 = (mt & 15) << 2;
        float4 r0 = *(const float4*)(aB + (size_t)(c0 + 0) * 4096 + w0);
        float4 r1 = *(const float4*)(aB + (size_t)(c0 + 1) * 4096 + w0);
        float4 r2 = *(const float4*)(aB + (size_t)(c0 + 2) * 4096 + w0);
        float4 r3 = *(const float4*)(aB + (size_t)(c0 + 3) * 4096 + w0);
        const float* f0 = (const float*)&r0;
        const float* f1 = (const float*)&r1;
        const float* f2 = (const float*)&r2;
        const float* f3 = (const float*)&r3;
        #pragma unroll
        for (int j = 0; j < 4; ++j) {
            ushort4 u = { f2bf(f0[j]), f2bf(f1[j]), f2bf(f2[j]), f2bf(f3[j]) };
            *(ushort4*)(AT + swzT(w0 + j, c0)) = u;
        }
    }
    __syncthreads();

    const int wv_ = tid >> 6;
    const int lane = tid & 63;
    const int l15 = lane & 15;
    const int g = lane >> 4;
    const int grp = wv_ >> 2;      // 0: T-proj + rank-1, 1: V-proj (regs)
    const int wl = wv_ & 3;        // wave index within group

    f32x4 vacc[4][4];              // grp1's V result, held across P3

    // ---- P2 || P4-compute on disjoint wave groups ----
    if (grp == 0) {
        // T = G*A: c1-strip wl*64..+63, all 4 x-tiles. D[row=c1][col=x].
        f32x4 acc[4][4];
        #pragma unroll
        for (int mi = 0; mi < 4; ++mi)
            #pragma unroll
            for (int n = 0; n < 4; ++n) acc[mi][n] = { 0.f, 0.f, 0.f, 0.f };
        const float sval = *(const float*)(wsb + 131584);
        f32x4 accu = { sval, sval, sval, sval };
        f32x4 accv = { 0.f, 0.f, 0.f, 0.f };

        #pragma unroll
        for (int kk = 0; kk < 8; ++kk) {
            bf16x8 atf[4];
            #pragma unroll
            for (int n = 0; n < 4; ++n)
                atf[n] = *(const bf16x8*)(AT + swzT(n * 16 + l15, kk * 32 + g * 8));
            bf16x8 uvbf = *(const bf16x8*)(AT + swzT(wl * 16 + l15, kk * 32 + g * 8));
            #pragma unroll
            for (int mi = 0; mi < 4; ++mi) {
                bf16x8 gfm = *(const bf16x8*)(Gb + (wl * 64 + mi * 16 + l15) * 256 + kk * 32 + g * 8);
                #pragma unroll
                for (int n = 0; n < 4; ++n)
                    acc[mi][n] = __builtin_amdgcn_mfma_f32_16x16x32_bf16(gfm, atf[n], acc[mi][n], 0, 0, 0);
            }
            bf16x8 uf = *(const bf16x8*)(ub + kk * 32 + g * 8);
            bf16x8 vf = *(const bf16x8*)(vbv + kk * 32 + g * 8);
            accu = __builtin_amdgcn_mfma_f32_16x16x32_bf16(uf, uvbf, accu, 0, 0, 0);
            accv = __builtin_amdgcn_mfma_f32_16x16x32_bf16(vf, uvbf, accv, 0, 0, 0);
        }
        // TT[x][c1] epilogue: ushort4 along c1 (= D rows)
        #pragma unroll
        for (int mi = 0; mi < 4; ++mi) {
            int c1_0 = wl * 64 + mi * 16 + g * 4;
            #pragma unroll
            for (int n = 0; n < 4; ++n) {
                ushort4 u = { f2bf(acc[mi][n][0]), f2bf(acc[mi][n][1]),
                              f2bf(acc[mi][n][2]), f2bf(acc[mi][n][3]) };
                *(ushort4*)(TT + swzT(n * 16 + l15, c1_0)) = u;
            }
        }
        if (g == 0) {
            uAvA[wl * 16 + l15] = accu[0];
            uAvA[64 + wl * 16 + l15] = accv[0];
        }
    } else {
        // V = Wv*A + bv: c-strip wl*64..+63, all 4 x-tiles. D[row=x][col=c].
        // Result stays in vacc; LDS write deferred until TT is dead.
        #pragma unroll
        for (int mi = 0; mi < 4; ++mi) {
            float bvl = bv[wl * 64 + mi * 16 + l15];
            #pragma unroll
            for (int n = 0; n < 4; ++n) vacc[mi][n] = { bvl, bvl, bvl, bvl };
        }
        #pragma unroll
        for (int kk = 0; kk < 8; ++kk) {
            bf16x8 atx[4];
            #pragma unroll
            for (int n = 0; n < 4; ++n)
                atx[n] = *(const bf16x8*)(AT + swzT(n * 16 + l15, kk * 32 + g * 8));
            #pragma unroll
            for (int mi = 0; mi < 4; ++mi) {
                bf16x8 wvf = *(const bf16x8*)(Wvb + (wl * 64 + mi * 16 + l15) * 256 + kk * 32 + g * 8);
                #pragma unroll
                for (int n = 0; n < 4; ++n)
                    vacc[mi][n] = __builtin_amdgcn_mfma_f32_16x16x32_bf16(atx[n], wvf, vacc[mi][n], 0, 0, 0);
            }
        }
    }
    __syncthreads();

    // ---- P3: attn = A^T T + rank-1 (D rows x, cols w), all 8 waves ----
    const int wt3 = wv_ >> 1;
    const int xb3 = (wv_ & 1) * 2;
    {
        f32x4 acc3[2] = { { 0, 0, 0, 0 }, { 0, 0, 0, 0 } };
        #pragma unroll
        for (int kk = 0; kk < 8; ++kk) {
            bf16x8 awf = *(const bf16x8*)(AT + swzT(wt3 * 16 + l15, kk * 32 + g * 8));
            #pragma unroll
            for (int j = 0; j < 2; ++j) {
                bf16x8 txf = *(const bf16x8*)(TT + swzT((xb3 + j) * 16 + l15, kk * 32 + g * 8));
                acc3[j] = __builtin_amdgcn_mfma_f32_16x16x32_bf16(txf, awf, acc3[j], 0, 0, 0);
            }
        }
        const int w = wt3 * 16 + l15;
        const float vAw = uAvA[64 + w];
        #pragma unroll
        for (int j = 0; j < 2; ++j) {
            int x0 = (xb3 + j) * 16 + g * 4;
            float4 uq = *(const float4*)&uAvA[x0];
            const float* uqa = (const float*)&uq;
            ushort4 u = { f2bf(acc3[j][0] + uqa[0] + vAw), f2bf(acc3[j][1] + uqa[1] + vAw),
                          f2bf(acc3[j][2] + uqa[2] + vAw), f2bf(acc3[j][3] + uqa[3] + vAw) };
            *(ushort4*)(ATT + swzS(w, x0)) = u;
        }
    }
    __syncthreads();   // all TT reads done -> Vs may now overwrite TT region

    // ---- residual loads (all waves, overlap) + grp1 writes Vs from vacc ----
    float4 res[2][4];
    #pragma unroll
    for (int mi = 0; mi < 2; ++mi) {
        int c = wv_ * 32 + mi * 16 + l15;
        #pragma unroll
        for (int n = 0; n < 4; ++n)
            res[mi][n] = *(const float4*)(aB + (size_t)c * 4096 + n * 16 + g * 4);
    }
    if (grp == 1) {
        #pragma unroll
        for (int mi = 0; mi < 4; ++mi) {
            int c = wl * 64 + mi * 16 + l15;
            #pragma unroll
            for (int n = 0; n < 4; ++n) {
                ushort4 u = { f2bf(vacc[mi][n][0]), f2bf(vacc[mi][n][1]),
                              f2bf(vacc[mi][n][2]), f2bf(vacc[mi][n][3]) };
                *(ushort4*)(Vs + swzS(c, n * 16 + g * 4)) = u;
            }
        }
    }
    __syncthreads();

    // ---- P5: O = ATT x Vs (D rows w, cols c), fp32 residual epilogue ----
    {
        f32x4 acc[2][4];
        #pragma unroll
        for (int mi = 0; mi < 2; ++mi)
            #pragma unroll
            for (int n = 0; n < 4; ++n) acc[mi][n] = { 0.f, 0.f, 0.f, 0.f };
        #pragma unroll
        for (int kk = 0; kk < 2; ++kk) {
            bf16x8 attf[4], vsf[2];
            #pragma unroll
            for (int n = 0; n < 4; ++n)
                attf[n] = *(const bf16x8*)(ATT + swzS(n * 16 + l15, kk * 32 + g * 8));
            #pragma unroll
            for (int mi = 0; mi < 2; ++mi)
                vsf[mi] = *(const bf16x8*)(Vs + swzS(wv_ * 32 + mi * 16 + l15, kk * 32 + g * 8));
            #pragma unroll
            for (int mi = 0; mi < 2; ++mi)
                #pragma unroll
                for (int n = 0; n < 4; ++n)
                    acc[mi][n] = __builtin_amdgcn_mfma_f32_16x16x32_bf16(attf[n], vsf[mi], acc[mi][n], 0, 0, 0);
        }
        float* outB = out + (size_t)b * (NC * NH * NW) + h * NW;
        #pragma unroll
        for (int mi = 0; mi < 2; ++mi) {
            int c = wv_ * 32 + mi * 16 + l15;
            float* po = outB + (size_t)c * 4096;
            #pragma unroll
            for (int n = 0; n < 4; ++n) {
                int w0 = n * 16 + g * 4;
                float4 o4;
                o4.x = res[mi][n].x + acc[mi][n][0];
                o4.y = res[mi][n].y + acc[mi][n][1];
                o4.z = res[mi][n].z + acc[mi][n][2];
                o4.w = res[mi][n].w + acc[mi][n][3];
                *(float4*)(po + w0) = o4;
            }
        }
    }
}

extern "C" void kernel_launch(void* const* d_in, const int* in_sizes, int n_in,
                              void* d_out, int out_size, void* d_ws, size_t ws_size,
                              hipStream_t stream) {
    (void)in_sizes; (void)n_in; (void)out_size; (void)ws_size;
    const float* a  = (const float*)d_in[0];
    const float* wq = (const float*)d_in[1];
    const float* bq = (const float*)d_in[2];
    const float* wk = (const float*)d_in[3];
    const float* bk = (const float*)d_in[4];
    const float* wv = (const float*)d_in[5];
    const float* bv = (const float*)d_in[6];
    float* out = (float*)d_out;
    unsigned short* wsb = (unsigned short*)d_ws;  // G | Wv_bf16 | u | v | s

    prep_g<<<dim3(33), dim3(256), 0, stream>>>(wq, wk, bq, bk, wsb);
    prep_wv<<<dim3(64), dim3(256), 0, stream>>>(wv, wsb);
    mha_fused<<<dim3(NB * NH), dim3(512), 0, stream>>>(a, wsb, bv, out);
}

// Round 8
// 94.858 us; speedup vs baseline: 1.1135x; 1.1135x over previous
//
#include <hip/hip_runtime.h>
#include <hip/hip_bf16.h>

#define NB 16
#define NC 256
#define NH 64
#define NW 64

typedef __attribute__((ext_vector_type(8))) short bf16x8;
typedef __attribute__((ext_vector_type(4))) float f32x4;

__device__ __forceinline__ unsigned short f2bf(float f) {
    union { float f; unsigned int u; } v; v.f = f;
    unsigned int u = v.u;
    u += 0x7fffu + ((u >> 16) & 1u);   // round-to-nearest-even
    return (unsigned short)(u >> 16);
}

// 16B-slot XOR swizzle; conflict-free for our write patterns, <=2-way reads
__device__ __forceinline__ int swzT(int row, int col) {   // [rows][256] tile
    return row * 256 + ((((col >> 3) ^ (row & 7) ^ ((row >> 3) & 7)) << 3) | (col & 7));
}
__device__ __forceinline__ int swzS(int row, int col) {   // [rows][64] tile
    return row * 64 + ((((col >> 3) ^ (row & 7) ^ ((row >> 3) & 7)) << 3) | (col & 7));
}

// ---- fused prep (1 launch): blocks 0..63 convert Wv; 64..95 compute G;
//      block 96 computes u = Wk^T bq, v = Wq^T bk, s = bq.bk ----
__global__ void prep(const float* __restrict__ wq, const float* __restrict__ wk,
                     const float* __restrict__ wv,
                     const float* __restrict__ bq, const float* __restrict__ bk,
                     unsigned short* __restrict__ wsb) {
    int bx = blockIdx.x;
    int t = threadIdx.x;
    if (bx < 64) {
        int i = bx * 256 + t;                 // 16384 float4s total
        float4 v4 = ((const float4*)wv)[i];
        ushort4 u = { f2bf(v4.x), f2bf(v4.y), f2bf(v4.z), f2bf(v4.w) };
        ((ushort4*)(wsb + 65536))[i] = u;
    } else if (bx < 96) {
        int c1_0 = (bx - 64) * 8;
        float acc[8] = {0.f, 0.f, 0.f, 0.f, 0.f, 0.f, 0.f, 0.f};
        for (int o = 0; o < 256; ++o) {
            float wkv = wk[o * 256 + t];
            #pragma unroll
            for (int i = 0; i < 8; ++i)
                acc[i] += wq[o * 256 + c1_0 + i] * wkv;
        }
        #pragma unroll
        for (int i = 0; i < 8; ++i)
            wsb[(c1_0 + i) * 256 + t] = f2bf(acc[i]);
    } else {
        float u = 0.f, v = 0.f;
        #pragma unroll 4
        for (int o = 0; o < 256; ++o) {
            u += bq[o] * wk[o * 256 + t];
            v += bk[o] * wq[o * 256 + t];
        }
        wsb[131072 + t] = f2bf(u);
        wsb[131328 + t] = f2bf(v);
        if (t == 0) {
            float s = 0.f;
            for (int o = 0; o < 256; ++o) s += bq[o] * bk[o];
            *(float*)(wsb + 131584) = s;
        }
    }
}

// LDS: AT [64 w][256 c] @0 | TT [64 x][256 c1] -> later Vs [256 c][64 x] @16384 |
//      ATT [64 w][64 x] @32768 | uAvA[128] f32.  Total 74,240 B -> 2 blocks/CU.
__launch_bounds__(512, 4)
__global__ void mha_fused(const float* __restrict__ a,
                          const unsigned short* __restrict__ wsb,
                          const float* __restrict__ bv,
                          float* __restrict__ out) {
    __shared__ __align__(16) unsigned short smem[36864];
    __shared__ __align__(16) float uAvA[128];
    unsigned short* AT  = smem;
    unsigned short* TT  = smem + 16384;
    unsigned short* Vs  = smem + 16384;   // aliases TT; written only in P4 (post-P3)
    unsigned short* ATT = smem + 32768;

    const unsigned short* Gb  = wsb;
    const unsigned short* Wvb = wsb + 65536;
    const unsigned short* ub  = wsb + 131072;
    const unsigned short* vbv = wsb + 131328;

    const int tid = threadIdx.x;
    const int b = blockIdx.x >> 6;
    const int h = blockIdx.x & 63;
    const float* aB = a + (size_t)b * (NC * NH * NW) + h * NW;

    // ---- P1: global [c][w] fp32 -> reg 4x4 transpose -> AT[w][c] bf16 ----
    #pragma unroll
    for (int half = 0; half < 2; ++half) {
        int mt = tid + half * 512;
        int c0 = (mt >> 4) << 2;
        int w0 = (mt & 15) << 2;
        float4 r0 = *(const float4*)(aB + (size_t)(c0 + 0) * 4096 + w0);
        float4 r1 = *(const float4*)(aB + (size_t)(c0 + 1) * 4096 + w0);
        float4 r2 = *(const float4*)(aB + (size_t)(c0 + 2) * 4096 + w0);
        float4 r3 = *(const float4*)(aB + (size_t)(c0 + 3) * 4096 + w0);
        const float* f0 = (const float*)&r0;
        const float* f1 = (const float*)&r1;
        const float* f2 = (const float*)&r2;
        const float* f3 = (const float*)&r3;
        #pragma unroll
        for (int j = 0; j < 4; ++j) {
            ushort4 u = { f2bf(f0[j]), f2bf(f1[j]), f2bf(f2[j]), f2bf(f3[j]) };
            *(ushort4*)(AT + swzT(w0 + j, c0)) = u;
        }
    }
    __syncthreads();

    const int wv_ = tid >> 6;
    const int lane = tid & 63;
    const int l15 = lane & 15;
    const int g = lane >> 4;

    // ---- P2: T = G*A (D rows c1, cols x) + rank-1 uA/vA; depth-1 weight prefetch ----
    {
        f32x4 acc[2][4];
        #pragma unroll
        for (int mi = 0; mi < 2; ++mi)
            #pragma unroll
            for (int n = 0; n < 4; ++n) acc[mi][n] = { 0.f, 0.f, 0.f, 0.f };

        const bool is_u = (wv_ < 4);
        const int uvrow = (wv_ & 3) * 16 + l15;
        const float sval = *(const float*)(wsb + 131584);
        f32x4 accu;
        #pragma unroll
        for (int r = 0; r < 4; ++r) accu[r] = is_u ? sval : 0.f;
        const unsigned short* uvp = is_u ? ub : vbv;

        const unsigned short* g0p = Gb + (wv_ * 32 + l15) * 256 + g * 8;
        const unsigned short* g1p = Gb + (wv_ * 32 + 16 + l15) * 256 + g * 8;
        bf16x8 gf0 = *(const bf16x8*)(g0p);
        bf16x8 gf1 = *(const bf16x8*)(g1p);
        bf16x8 uvf = *(const bf16x8*)(uvp + g * 8);

        #pragma unroll
        for (int kk = 0; kk < 8; ++kk) {
            bf16x8 cg0 = gf0, cg1 = gf1, cuv = uvf;
            if (kk < 7) {
                gf0 = *(const bf16x8*)(g0p + (kk + 1) * 32);
                gf1 = *(const bf16x8*)(g1p + (kk + 1) * 32);
                uvf = *(const bf16x8*)(uvp + (kk + 1) * 32 + g * 8);
            }
            bf16x8 atf[4];
            #pragma unroll
            for (int n = 0; n < 4; ++n)
                atf[n] = *(const bf16x8*)(AT + swzT(n * 16 + l15, kk * 32 + g * 8));
            bf16x8 uvbf = *(const bf16x8*)(AT + swzT(uvrow, kk * 32 + g * 8));
            #pragma unroll
            for (int n = 0; n < 4; ++n)
                acc[0][n] = __builtin_amdgcn_mfma_f32_16x16x32_bf16(cg0, atf[n], acc[0][n], 0, 0, 0);
            #pragma unroll
            for (int n = 0; n < 4; ++n)
                acc[1][n] = __builtin_amdgcn_mfma_f32_16x16x32_bf16(cg1, atf[n], acc[1][n], 0, 0, 0);
            accu = __builtin_amdgcn_mfma_f32_16x16x32_bf16(cuv, uvbf, accu, 0, 0, 0);
        }
        // TT[x][c1] epilogue: ushort4 along c1 (= D rows)
        #pragma unroll
        for (int mi = 0; mi < 2; ++mi) {
            int c1_0 = wv_ * 32 + mi * 16 + g * 4;
            #pragma unroll
            for (int n = 0; n < 4; ++n) {
                ushort4 u = { f2bf(acc[mi][n][0]), f2bf(acc[mi][n][1]),
                              f2bf(acc[mi][n][2]), f2bf(acc[mi][n][3]) };
                *(ushort4*)(TT + swzT(n * 16 + l15, c1_0)) = u;
            }
        }
        if (g == 0)
            uAvA[(is_u ? 0 : 64) + uvrow] = accu[0];
    }
    __syncthreads();

    // ---- P3: attn = A^T T + rank-1 (D rows x, cols w) ----
    const int wt3 = wv_ >> 1;
    const int xb3 = (wv_ & 1) * 2;
    {
        f32x4 acc3[2] = { { 0, 0, 0, 0 }, { 0, 0, 0, 0 } };
        #pragma unroll
        for (int kk = 0; kk < 8; ++kk) {
            bf16x8 awf = *(const bf16x8*)(AT + swzT(wt3 * 16 + l15, kk * 32 + g * 8));
            #pragma unroll
            for (int j = 0; j < 2; ++j) {
                bf16x8 txf = *(const bf16x8*)(TT + swzT((xb3 + j) * 16 + l15, kk * 32 + g * 8));
                acc3[j] = __builtin_amdgcn_mfma_f32_16x16x32_bf16(txf, awf, acc3[j], 0, 0, 0);
            }
        }
        const int w = wt3 * 16 + l15;
        const float vAw = uAvA[64 + w];
        #pragma unroll
        for (int j = 0; j < 2; ++j) {
            int x0 = (xb3 + j) * 16 + g * 4;
            float4 uq = *(const float4*)&uAvA[x0];
            const float* uqa = (const float*)&uq;
            ushort4 u = { f2bf(acc3[j][0] + uqa[0] + vAw), f2bf(acc3[j][1] + uqa[1] + vAw),
                          f2bf(acc3[j][2] + uqa[2] + vAw), f2bf(acc3[j][3] + uqa[3] + vAw) };
            *(ushort4*)(ATT + swzS(w, x0)) = u;
        }
    }
    __syncthreads();   // all TT reads done -> P4 may overwrite with Vs

    // ---- P4: Vs = Wv*A + bv (D rows x, cols c); residual loads issued first ----
    float4 res[2][4];
    #pragma unroll
    for (int mi = 0; mi < 2; ++mi) {
        int c = wv_ * 32 + mi * 16 + l15;
        #pragma unroll
        for (int n = 0; n < 4; ++n)
            res[mi][n] = *(const float4*)(aB + (size_t)c * 4096 + n * 16 + g * 4);
    }
    {
        f32x4 acc[2][4];
        #pragma unroll
        for (int mi = 0; mi < 2; ++mi) {
            float bvl = bv[wv_ * 32 + mi * 16 + l15];
            #pragma unroll
            for (int n = 0; n < 4; ++n) acc[mi][n] = { bvl, bvl, bvl, bvl };
        }
        const unsigned short* w0p = Wvb + (wv_ * 32 + l15) * 256 + g * 8;
        const unsigned short* w1p = Wvb + (wv_ * 32 + 16 + l15) * 256 + g * 8;
        bf16x8 wf0 = *(const bf16x8*)(w0p);
        bf16x8 wf1 = *(const bf16x8*)(w1p);
        #pragma unroll
        for (int kk = 0; kk < 8; ++kk) {
            bf16x8 cw0 = wf0, cw1 = wf1;
            if (kk < 7) {
                wf0 = *(const bf16x8*)(w0p + (kk + 1) * 32);
                wf1 = *(const bf16x8*)(w1p + (kk + 1) * 32);
            }
            bf16x8 atx[4];
            #pragma unroll
            for (int n = 0; n < 4; ++n)
                atx[n] = *(const bf16x8*)(AT + swzT(n * 16 + l15, kk * 32 + g * 8));
            #pragma unroll
            for (int n = 0; n < 4; ++n)
                acc[0][n] = __builtin_amdgcn_mfma_f32_16x16x32_bf16(atx[n], cw0, acc[0][n], 0, 0, 0);
            #pragma unroll
            for (int n = 0; n < 4; ++n)
                acc[1][n] = __builtin_amdgcn_mfma_f32_16x16x32_bf16(atx[n], cw1, acc[1][n], 0, 0, 0);
        }
        #pragma unroll
        for (int mi = 0; mi < 2; ++mi) {
            int c = wv_ * 32 + mi * 16 + l15;
            #pragma unroll
            for (int n = 0; n < 4; ++n) {
                ushort4 u = { f2bf(acc[mi][n][0]), f2bf(acc[mi][n][1]),
                              f2bf(acc[mi][n][2]), f2bf(acc[mi][n][3]) };
                *(ushort4*)(Vs + swzS(c, n * 16 + g * 4)) = u;
            }
        }
    }
    __syncthreads();

    // ---- P5: O = ATT x Vs (D rows w, cols c), fp32 residual epilogue ----
    {
        f32x4 acc[2][4];
        #pragma unroll
        for (int mi = 0; mi < 2; ++mi)
            #pragma unroll
            for (int n = 0; n < 4; ++n) acc[mi][n] = { 0.f, 0.f, 0.f, 0.f };
        #pragma unroll
        for (int kk = 0; kk < 2; ++kk) {
            bf16x8 attf[4], vsf[2];
            #pragma unroll
            for (int n = 0; n < 4; ++n)
                attf[n] = *(const bf16x8*)(ATT + swzS(n * 16 + l15, kk * 32 + g * 8));
            #pragma unroll
            for (int mi = 0; mi < 2; ++mi)
                vsf[mi] = *(const bf16x8*)(Vs + swzS(wv_ * 32 + mi * 16 + l15, kk * 32 + g * 8));
            #pragma unroll
            for (int mi = 0; mi < 2; ++mi)
                #pragma unroll
                for (int n = 0; n < 4; ++n)
                    acc[mi][n] = __builtin_amdgcn_mfma_f32_16x16x32_bf16(attf[n], vsf[mi], acc[mi][n], 0, 0, 0);
        }
        float* outB = out + (size_t)b * (NC * NH * NW) + h * NW;
        #pragma unroll
        for (int mi = 0; mi < 2; ++mi) {
            int c = wv_ * 32 + mi * 16 + l15;
            float* po = outB + (size_t)c * 4096;
            #pragma unroll
            for (int n = 0; n < 4; ++n) {
                int w0 = n * 16 + g * 4;
                float4 o4;
                o4.x = res[mi][n].x + acc[mi][n][0];
                o4.y = res[mi][n].y + acc[mi][n][1];
                o4.z = res[mi][n].z + acc[mi][n][2];
                o4.w = res[mi][n].w + acc[mi][n][3];
                *(float4*)(po + w0) = o4;
            }
        }
    }
}

extern "C" void kernel_launch(void* const* d_in, const int* in_sizes, int n_in,
                              void* d_out, int out_size, void* d_ws, size_t ws_size,
                              hipStream_t stream) {
    (void)in_sizes; (void)n_in; (void)out_size; (void)ws_size;
    const float* a  = (const float*)d_in[0];
    const float* wq = (const float*)d_in[1];
    const float* bq = (const float*)d_in[2];
    const float* wk = (const float*)d_in[3];
    const float* bk = (const float*)d_in[4];
    const float* wv = (const float*)d_in[5];
    const float* bv = (const float*)d_in[6];
    float* out = (float*)d_out;
    unsigned short* wsb = (unsigned short*)d_ws;  // G | Wv_bf16 | u | v | s

    prep<<<dim3(97), dim3(256), 0, stream>>>(wq, wk, wv, bq, bk, wsb);
    mha_fused<<<dim3(NB * NH), dim3(512), 0, stream>>>(a, wsb, bv, out);
}